// Round 4
// baseline (40.571 us; speedup 1.0000x reference)
//
#include <hip/hip_runtime.h>

// Exact-rounding 3-component squared sum in reference order: (x*x + y*y) + z*z
static __device__ __forceinline__ float sq3(float x, float y, float z) {
    return __fadd_rn(__fadd_rn(__fmul_rn(x, x), __fmul_rn(y, y)), __fmul_rn(z, z));
}

// ---------------- Kernel 1: per-row H_i + packed gather table ----------------
// T[2*row]   = (Cjx, Cjy, Cjz, Ojx)
// T[2*row+1] = (Ojy, Ojz, asfloat(C[row]), 0)
__global__ __launch_bounds__(256) void setup_kernel(
    const float* __restrict__ X,
    const int*   __restrict__ C,
    float*  __restrict__ outH,
    float4* __restrict__ T,        // may be null (fallback mode)
    int N, int rows)
{
    const float EPS   = 0.001f;
    const float LENNH = 1.015f;

    int row = blockIdx.x * blockDim.x + threadIdx.x;
    if (row >= rows) return;
    int i = row & (N - 1);

    const float* xi = X + (size_t)row * 12;
    float4 a4  = *(const float4*)xi;        // N.xyz, Ca.x
    float2 a2  = *(const float2*)(xi + 4);  // Ca.y, Ca.z
    float2 c01 = *(const float2*)(xi + 6);  // C.x, C.y
    float4 co  = *(const float4*)(xi + 8);  // C.z, O.xyz
    float nx = a4.x, ny = a4.y, nz = a4.z;
    float cax = a4.w, cay = a2.x, caz = a2.y;

    if (T) {
        T[2 * (size_t)row]     = make_float4(c01.x, c01.y, co.x, co.y);
        T[2 * (size_t)row + 1] = make_float4(co.z, co.w, __int_as_float(C[row]), 0.0f);
    }

    int prow = (i == 0) ? row : row - 1;
    const float* xp = X + (size_t)prow * 12;
    float2 p2 = *(const float2*)(xp + 6);
    float px = p2.x, py = p2.y, pz = xp[8];

    // u1 = normed(N - Cprev)
    float ax = __fsub_rn(nx, px), ay = __fsub_rn(ny, py), az = __fsub_rn(nz, pz);
    float s1 = __fsqrt_rn(__fadd_rn(sq3(ax, ay, az), EPS));
    ax = __fdiv_rn(ax, s1); ay = __fdiv_rn(ay, s1); az = __fdiv_rn(az, s1);
    // u2 = normed(N - Ca)
    float bx = __fsub_rn(nx, cax), by = __fsub_rn(ny, cay), bz = __fsub_rn(nz, caz);
    float s2 = __fsqrt_rn(__fadd_rn(sq3(bx, by, bz), EPS));
    bx = __fdiv_rn(bx, s2); by = __fdiv_rn(by, s2); bz = __fdiv_rn(bz, s2);
    // u = normed(u1 + u2)
    float ux = __fadd_rn(ax, bx), uy = __fadd_rn(ay, by), uz = __fadd_rn(az, bz);
    float s3 = __fsqrt_rn(__fadd_rn(sq3(ux, uy, uz), EPS));
    ux = __fdiv_rn(ux, s3); uy = __fdiv_rn(uy, s3); uz = __fdiv_rn(uz, s3);

    float* ho = outH + (size_t)row * 3;
    ho[0] = __fadd_rn(nx, __fmul_rn(LENNH, ux));
    ho[1] = __fadd_rn(ny, __fmul_rn(LENNH, uy));
    ho[2] = __fadd_rn(nz, __fmul_rn(LENNH, uz));
}

// Per-edge math, bit-exact reference order.
static __device__ __forceinline__ void edge_math(
    float nx, float ny, float nz, float hx, float hy, float hz,
    int Ci, int i, int j, float mij, float4 t0, float4 t1,
    float& hb, float& mhb)
{
    const float EPS   = 0.001f;
    const float COEFF = (float)(0.42 * 0.2 * 332.0);   // 27.888f

    float cjx = t0.x, cjy = t0.y, cjz = t0.z;
    float ojx = t0.w, ojy = t1.x, ojz = t1.y;
    int   Cn  = __float_as_int(t1.z);

    float dx = __fsub_rn(nx, ojx), dy = __fsub_rn(ny, ojy), dz = __fsub_rn(nz, ojz);
    float dno = __fsqrt_rn(__fadd_rn(sq3(dx, dy, dz), EPS));
    float iNO = __fdiv_rn(1.0f, dno);
    dx = __fsub_rn(nx, cjx); dy = __fsub_rn(ny, cjy); dz = __fsub_rn(nz, cjz);
    float iNC = __fdiv_rn(1.0f, __fsqrt_rn(__fadd_rn(sq3(dx, dy, dz), EPS)));
    dx = __fsub_rn(hx, cjx); dy = __fsub_rn(hy, cjy); dz = __fsub_rn(hz, cjz);
    float iHC = __fdiv_rn(1.0f, __fsqrt_rn(__fadd_rn(sq3(dx, dy, dz), EPS)));
    dx = __fsub_rn(hx, ojx); dy = __fsub_rn(hy, ojy); dz = __fsub_rn(hz, ojz);
    float iHO = __fdiv_rn(1.0f, __fsqrt_rn(__fadd_rn(sq3(dx, dy, dz), EPS)));

    float U = __fmul_rn(COEFF, __fsub_rn(__fadd_rn(__fsub_rn(iNO, iNC), iHC), iHO));

    int dij = j - i; if (dij < 0) dij = -dij;
    float m_local    = ((dij < 3) && (Ci == Cn)) ? 1.0f : 0.0f;
    float m_nonlocal = __fsub_rn(1.0f, m_local);
    float m_cutD     = (dno < 3.6f) ? 1.0f : 0.0f;
    float m_i        = (Ci > 0) ? 1.0f : 0.0f;
    float m_int      = __fmul_rn(m_i, (Cn > 0) ? 1.0f : 0.0f);

    mhb = __fmul_rn(__fmul_rn(__fmul_rn(mij, m_nonlocal), m_cutD), m_int);
    hb  = __fmul_rn(mhb, (U < -0.5f) ? 1.0f : 0.0f);
}

// ------- Kernel 2: lane-pair cooperative gather (1 line transaction / edge) -------
// One wave per row. Lanes 2e,2e+1 jointly fetch edge e's 32-B table entry
// (both halves in the same 64-B line -> coalesce to one L1 transaction),
// exchange halves via shfl_xor, each computes the edge fully, both store
// identical values (same address, same data -> well-defined).
__global__ __launch_bounds__(256) void edge_kernel_pair(
    const int*   __restrict__ C,
    const int*   __restrict__ E,
    const float* __restrict__ M,
    const float* __restrict__ H,
    const float* __restrict__ X,
    const float4* __restrict__ T,
    float* __restrict__ outHB,
    float* __restrict__ outMK,
    int N, int rows)
{
    int gtid = blockIdx.x * blockDim.x + threadIdx.x;
    int row  = gtid >> 6;
    if (row >= rows) return;
    int lane = threadIdx.x & 63;
    int i = row & (N - 1);
    int b = row >> 14;

    int urow = __builtin_amdgcn_readfirstlane(row);
    const float* xi = X + (size_t)urow * 12;
    float nx = xi[0], ny = xi[1], nz = xi[2];
    const float* hi = H + (size_t)urow * 3;
    float hx = hi[0], hy = hi[1], hz = hi[2];
    int Ci = C[urow];

    size_t base = (size_t)row * 64;
    // fully-coalesced loads of all 64 edge indices / masks for this row
    int   jall = E[base + lane];
    float mall = M[base + lane];

    const float4* Tb = T + ((size_t)b << 15);   // 2*N float4 per batch
    int half = lane & 1;
    int e0 = lane >> 1;          // round-0 edge for this pair
    int e1 = 32 + e0;            // round-1 edge

    int   j0 = __shfl(jall, e0, 64);
    int   j1 = __shfl(jall, e1, 64);
    float m0 = __shfl(mall, e0, 64);
    float m1 = __shfl(mall, e1, 64);

    // Issue both gathers up front (MLP); each pair hits one 64-B line.
    float4 mine0 = Tb[2 * (size_t)j0 + half];
    float4 mine1 = Tb[2 * (size_t)j1 + half];

    // exchange halves within the pair
    float4 oth0, oth1;
    oth0.x = __shfl_xor(mine0.x, 1, 64);
    oth0.y = __shfl_xor(mine0.y, 1, 64);
    oth0.z = __shfl_xor(mine0.z, 1, 64);
    oth0.w = __shfl_xor(mine0.w, 1, 64);
    oth1.x = __shfl_xor(mine1.x, 1, 64);
    oth1.y = __shfl_xor(mine1.y, 1, 64);
    oth1.z = __shfl_xor(mine1.z, 1, 64);
    oth1.w = __shfl_xor(mine1.w, 1, 64);

    float4 t0a = half ? oth0 : mine0;
    float4 t1a = half ? mine0 : oth0;
    float4 t0b = half ? oth1 : mine1;
    float4 t1b = half ? mine1 : oth1;

    float hb0, mk0, hb1, mk1;
    edge_math(nx, ny, nz, hx, hy, hz, Ci, i, j0, m0, t0a, t1a, hb0, mk0);
    edge_math(nx, ny, nz, hx, hy, hz, Ci, i, j1, m1, t0b, t1b, hb1, mk1);

    // duplicated stores: lanes 2e,2e+1 write the same value to the same address
    outHB[base + e0] = hb0;
    outMK[base + e0] = mk0;
    outHB[base + e1] = hb1;
    outMK[base + e1] = mk1;
}

// ---------------- Fallback kernel (no workspace): R2 path, known-good ----------------
__global__ __launch_bounds__(256) void edge_kernel_noT(
    const float* __restrict__ X,
    const int*   __restrict__ C,
    const int*   __restrict__ E,
    const float* __restrict__ M,
    const float* __restrict__ H,
    float* __restrict__ outHB,
    float* __restrict__ outMK,
    int N, int rows)
{
    int tid = blockIdx.x * blockDim.x + threadIdx.x;
    int row = tid >> 6;
    if (row >= rows) return;
    int k = tid & 63;
    int i = row & (N - 1);
    int b = row >> 14;

    int urow = __builtin_amdgcn_readfirstlane(row);
    const float* xi = X + (size_t)urow * 12;
    float nx = xi[0], ny = xi[1], nz = xi[2];
    const float* hi = H + (size_t)urow * 3;
    float hx = hi[0], hy = hi[1], hz = hi[2];
    int Ci = C[urow];

    size_t eoff = (size_t)row * 64 + (size_t)k;
    int j = E[eoff];
    float mij = M[eoff];

    const float* xj = X + ((size_t)b * (size_t)N + (size_t)j) * 12;
    float2 cj01 = *(const float2*)(xj + 6);
    float4 v4   = *(const float4*)(xj + 8);
    int Cn = C[(size_t)b * (size_t)N + (size_t)j];

    float4 t0 = make_float4(cj01.x, cj01.y, v4.x, v4.y);
    float4 t1 = make_float4(v4.z, v4.w, __int_as_float(Cn), 0.0f);
    float hb, mhb;
    edge_math(nx, ny, nz, hx, hy, hz, Ci, i, j, mij, t0, t1, hb, mhb);

    outHB[eoff] = hb;
    outMK[eoff] = mhb;
}

extern "C" void kernel_launch(void* const* d_in, const int* in_sizes, int n_in,
                              void* d_out, int out_size, void* d_ws, size_t ws_size,
                              hipStream_t stream) {
    const float* X = (const float*)d_in[0];
    const int*   C = (const int*)d_in[1];
    const int*   E = (const int*)d_in[2];
    const float* M = (const float*)d_in[3];

    int rows = in_sizes[1];          // B*N = 65536
    int BNK  = in_sizes[2];          // B*N*K
    const int N = 16384;

    float* out   = (float*)d_out;
    float* outHB = out;
    float* outMK = out + (size_t)BNK;
    float* outH  = out + 2 * (size_t)BNK;

    size_t tbytes = (size_t)rows * 32;
    bool useT = (ws_size >= tbytes) && (d_ws != nullptr);
    float4* T = useT ? (float4*)d_ws : nullptr;

    {
        int block = 256;
        int grid  = (rows + block - 1) / block;
        hipLaunchKernelGGL(setup_kernel, dim3(grid), dim3(block), 0, stream,
                           X, C, outH, T, N, rows);
    }
    if (useT) {
        int total = rows * 64;       // one wave (64 lanes) per row
        int block = 256;
        int grid  = (total + block - 1) / block;
        hipLaunchKernelGGL(edge_kernel_pair, dim3(grid), dim3(block), 0, stream,
                           C, E, M, outH, X, T, outHB, outMK, N, rows);
    } else {
        int total = rows * 64;
        int block = 256;
        int grid  = (total + block - 1) / block;
        hipLaunchKernelGGL(edge_kernel_noT, dim3(grid), dim3(block), 0, stream,
                           X, C, E, M, outH, outHB, outMK, N, rows);
    }
}

// Round 5
// 34.568 us; speedup vs baseline: 1.1736x; 1.1736x over previous
//
#include <hip/hip_runtime.h>

// Exact-rounding 3-component squared sum in reference order: (x*x + y*y) + z*z
static __device__ __forceinline__ float sq3(float x, float y, float z) {
    return __fadd_rn(__fadd_rn(__fmul_rn(x, x), __fmul_rn(y, y)), __fmul_rn(z, z));
}

// ---------------- Kernel 1: per-row H_i + packed gather table ----------------
// T[2*row]   = (Cjx, Cjy, Cjz, Ojx)
// T[2*row+1] = (Ojy, Ojz, asfloat(C[row]), 0)
__global__ __launch_bounds__(256) void setup_kernel(
    const float* __restrict__ X,
    const int*   __restrict__ C,
    float*  __restrict__ outH,
    float4* __restrict__ T,        // may be null (fallback mode)
    int N, int rows)
{
    const float EPS   = 0.001f;
    const float LENNH = 1.015f;

    int row = blockIdx.x * blockDim.x + threadIdx.x;
    if (row >= rows) return;
    int i = row & (N - 1);

    const float* xi = X + (size_t)row * 12;
    float4 a4  = *(const float4*)xi;        // N.xyz, Ca.x
    float2 a2  = *(const float2*)(xi + 4);  // Ca.y, Ca.z
    float2 c01 = *(const float2*)(xi + 6);  // C.x, C.y
    float4 co  = *(const float4*)(xi + 8);  // C.z, O.xyz
    float nx = a4.x, ny = a4.y, nz = a4.z;
    float cax = a4.w, cay = a2.x, caz = a2.y;

    if (T) {
        T[2 * (size_t)row]     = make_float4(c01.x, c01.y, co.x, co.y);
        T[2 * (size_t)row + 1] = make_float4(co.z, co.w, __int_as_float(C[row]), 0.0f);
    }

    int prow = (i == 0) ? row : row - 1;
    const float* xp = X + (size_t)prow * 12;
    float2 p2 = *(const float2*)(xp + 6);
    float px = p2.x, py = p2.y, pz = xp[8];

    // u1 = normed(N - Cprev)
    float ax = __fsub_rn(nx, px), ay = __fsub_rn(ny, py), az = __fsub_rn(nz, pz);
    float s1 = __fsqrt_rn(__fadd_rn(sq3(ax, ay, az), EPS));
    ax = __fdiv_rn(ax, s1); ay = __fdiv_rn(ay, s1); az = __fdiv_rn(az, s1);
    // u2 = normed(N - Ca)
    float bx = __fsub_rn(nx, cax), by = __fsub_rn(ny, cay), bz = __fsub_rn(nz, caz);
    float s2 = __fsqrt_rn(__fadd_rn(sq3(bx, by, bz), EPS));
    bx = __fdiv_rn(bx, s2); by = __fdiv_rn(by, s2); bz = __fdiv_rn(bz, s2);
    // u = normed(u1 + u2)
    float ux = __fadd_rn(ax, bx), uy = __fadd_rn(ay, by), uz = __fadd_rn(az, bz);
    float s3 = __fsqrt_rn(__fadd_rn(sq3(ux, uy, uz), EPS));
    ux = __fdiv_rn(ux, s3); uy = __fdiv_rn(uy, s3); uz = __fdiv_rn(uz, s3);

    float* ho = outH + (size_t)row * 3;
    ho[0] = __fadd_rn(nx, __fmul_rn(LENNH, ux));
    ho[1] = __fadd_rn(ny, __fmul_rn(LENNH, uy));
    ho[2] = __fadd_rn(nz, __fmul_rn(LENNH, uz));
}

// Per-edge math, bit-exact reference order.
static __device__ __forceinline__ void edge_math(
    float nx, float ny, float nz, float hx, float hy, float hz,
    int Ci, int i, int j, float mij, float4 t0, float4 t1,
    float& hb, float& mhb)
{
    const float EPS   = 0.001f;
    const float COEFF = (float)(0.42 * 0.2 * 332.0);   // 27.888f

    float cjx = t0.x, cjy = t0.y, cjz = t0.z;
    float ojx = t0.w, ojy = t1.x, ojz = t1.y;
    int   Cn  = __float_as_int(t1.z);

    float dx = __fsub_rn(nx, ojx), dy = __fsub_rn(ny, ojy), dz = __fsub_rn(nz, ojz);
    float dno = __fsqrt_rn(__fadd_rn(sq3(dx, dy, dz), EPS));
    float iNO = __fdiv_rn(1.0f, dno);
    dx = __fsub_rn(nx, cjx); dy = __fsub_rn(ny, cjy); dz = __fsub_rn(nz, cjz);
    float iNC = __fdiv_rn(1.0f, __fsqrt_rn(__fadd_rn(sq3(dx, dy, dz), EPS)));
    dx = __fsub_rn(hx, cjx); dy = __fsub_rn(hy, cjy); dz = __fsub_rn(hz, cjz);
    float iHC = __fdiv_rn(1.0f, __fsqrt_rn(__fadd_rn(sq3(dx, dy, dz), EPS)));
    dx = __fsub_rn(hx, ojx); dy = __fsub_rn(hy, ojy); dz = __fsub_rn(hz, ojz);
    float iHO = __fdiv_rn(1.0f, __fsqrt_rn(__fadd_rn(sq3(dx, dy, dz), EPS)));

    float U = __fmul_rn(COEFF, __fsub_rn(__fadd_rn(__fsub_rn(iNO, iNC), iHC), iHO));

    int dij = j - i; if (dij < 0) dij = -dij;
    float m_local    = ((dij < 3) && (Ci == Cn)) ? 1.0f : 0.0f;
    float m_nonlocal = __fsub_rn(1.0f, m_local);
    float m_cutD     = (dno < 3.6f) ? 1.0f : 0.0f;
    float m_i        = (Ci > 0) ? 1.0f : 0.0f;
    float m_int      = __fmul_rn(m_i, (Cn > 0) ? 1.0f : 0.0f);

    mhb = __fmul_rn(__fmul_rn(__fmul_rn(mij, m_nonlocal), m_cutD), m_int);
    hb  = __fmul_rn(mhb, (U < -0.5f) ? 1.0f : 0.0f);
}

static __device__ __forceinline__ float4 shflxor4(float4 v, int m) {
    float4 r;
    r.x = __shfl_xor(v.x, m, 64);
    r.y = __shfl_xor(v.y, m, 64);
    r.z = __shfl_xor(v.z, m, 64);
    r.w = __shfl_xor(v.w, m, 64);
    return r;
}

// ------- Kernel 2: adjacent-pair cooperative gather, NO redundant math -------
// One wave per row (64 edges). Two gather rounds:
//   round A: lane l loads half (l&1)   of edge (l>>1)'s 32-B entry
//   round B: lane l loads half (l&1)^1 of edge 32+(l>>1)'s entry
// Adjacent lanes hit the same 64-B line -> 1 line transaction per edge.
// After one shfl_xor(1) swap per round: even lanes own edge l>>1 fully,
// odd lanes own edge 32+(l>>1) fully. Each edge computed exactly once.
// Two final shuffles restore lane order for coalesced stores.
__global__ __launch_bounds__(256) void edge_kernel_pair2(
    const int*   __restrict__ C,
    const int*   __restrict__ E,
    const float* __restrict__ M,
    const float* __restrict__ H,
    const float* __restrict__ X,
    const float4* __restrict__ T,
    float* __restrict__ outHB,
    float* __restrict__ outMK,
    int N, int rows)
{
    int gtid = blockIdx.x * blockDim.x + threadIdx.x;
    int row  = gtid >> 6;
    if (row >= rows) return;
    int lane = threadIdx.x & 63;
    int i = row & (N - 1);
    int b = row >> 14;

    int urow = __builtin_amdgcn_readfirstlane(row);
    const float* xi = X + (size_t)urow * 12;
    float nx = xi[0], ny = xi[1], nz = xi[2];
    const float* hi = H + (size_t)urow * 3;
    float hx = hi[0], hy = hi[1], hz = hi[2];
    int Ci = C[urow];

    size_t base = (size_t)row * 64;
    int   jall = E[base + lane];     // coalesced
    float mall = M[base + lane];     // coalesced

    int e    = lane >> 1;            // pair id: 0..31
    int half = lane & 1;

    int jA = __shfl(jall, e, 64);        // j of edge e
    int jB = __shfl(jall, 32 + e, 64);   // j of edge 32+e

    const float4* Tb = T + ((size_t)b << 15);   // 2*N float4 per batch
    // Issue both gathers up front (independent; each pair -> one 64-B line)
    float4 vA = Tb[2 * (size_t)jA + half];
    float4 vB = Tb[2 * (size_t)jB + (half ^ 1)];

    float4 vAx = shflxor4(vA, 1);
    float4 vBx = shflxor4(vB, 1);

    // even lane computes edge e (t0=vA, t1=vAx); odd computes 32+e (t0=vB, t1=vBx)
    int   eMine = half ? (32 + e) : e;
    int   jMine = half ? jB : jA;
    float mMine = __shfl(mall, eMine, 64);
    float4 t0 = half ? vB : vA;
    float4 t1 = half ? vBx : vAx;

    float hb, mk;
    edge_math(nx, ny, nz, hx, hy, hz, Ci, i, jMine, mMine, t0, t1, hb, mk);

    // reorder: edge l lives at lane (l<32 ? 2l : 2*(l-32)+1)
    int src = (lane < 32) ? (lane << 1) : (((lane & 31) << 1) | 1);
    float hbO = __shfl(hb, src, 64);
    float mkO = __shfl(mk, src, 64);

    outHB[base + lane] = hbO;
    outMK[base + lane] = mkO;
}

// ---------------- Fallback kernel (no workspace): R2 path, known-good ----------------
__global__ __launch_bounds__(256) void edge_kernel_noT(
    const float* __restrict__ X,
    const int*   __restrict__ C,
    const int*   __restrict__ E,
    const float* __restrict__ M,
    const float* __restrict__ H,
    float* __restrict__ outHB,
    float* __restrict__ outMK,
    int N, int rows)
{
    int tid = blockIdx.x * blockDim.x + threadIdx.x;
    int row = tid >> 6;
    if (row >= rows) return;
    int k = tid & 63;
    int i = row & (N - 1);
    int b = row >> 14;

    int urow = __builtin_amdgcn_readfirstlane(row);
    const float* xi = X + (size_t)urow * 12;
    float nx = xi[0], ny = xi[1], nz = xi[2];
    const float* hi = H + (size_t)urow * 3;
    float hx = hi[0], hy = hi[1], hz = hi[2];
    int Ci = C[urow];

    size_t eoff = (size_t)row * 64 + (size_t)k;
    int j = E[eoff];
    float mij = M[eoff];

    const float* xj = X + ((size_t)b * (size_t)N + (size_t)j) * 12;
    float2 cj01 = *(const float2*)(xj + 6);
    float4 v4   = *(const float4*)(xj + 8);
    int Cn = C[(size_t)b * (size_t)N + (size_t)j];

    float4 t0 = make_float4(cj01.x, cj01.y, v4.x, v4.y);
    float4 t1 = make_float4(v4.z, v4.w, __int_as_float(Cn), 0.0f);
    float hb, mhb;
    edge_math(nx, ny, nz, hx, hy, hz, Ci, i, j, mij, t0, t1, hb, mhb);

    outHB[eoff] = hb;
    outMK[eoff] = mhb;
}

extern "C" void kernel_launch(void* const* d_in, const int* in_sizes, int n_in,
                              void* d_out, int out_size, void* d_ws, size_t ws_size,
                              hipStream_t stream) {
    const float* X = (const float*)d_in[0];
    const int*   C = (const int*)d_in[1];
    const int*   E = (const int*)d_in[2];
    const float* M = (const float*)d_in[3];

    int rows = in_sizes[1];          // B*N = 65536
    int BNK  = in_sizes[2];          // B*N*K
    const int N = 16384;

    float* out   = (float*)d_out;
    float* outHB = out;
    float* outMK = out + (size_t)BNK;
    float* outH  = out + 2 * (size_t)BNK;

    size_t tbytes = (size_t)rows * 32;
    bool useT = (ws_size >= tbytes) && (d_ws != nullptr);
    float4* T = useT ? (float4*)d_ws : nullptr;

    {
        int block = 256;
        int grid  = (rows + block - 1) / block;
        hipLaunchKernelGGL(setup_kernel, dim3(grid), dim3(block), 0, stream,
                           X, C, outH, T, N, rows);
    }
    if (useT) {
        int total = rows * 64;       // one wave (64 lanes) per row
        int block = 256;
        int grid  = (total + block - 1) / block;
        hipLaunchKernelGGL(edge_kernel_pair2, dim3(grid), dim3(block), 0, stream,
                           C, E, M, outH, X, T, outHB, outMK, N, rows);
    } else {
        int total = rows * 64;
        int block = 256;
        int grid  = (total + block - 1) / block;
        hipLaunchKernelGGL(edge_kernel_noT, dim3(grid), dim3(block), 0, stream,
                           X, C, E, M, outH, outHB, outMK, N, rows);
    }
}